// Round 9
// baseline (349.502 us; speedup 1.0000x reference)
//
#include <hip/hip_runtime.h>

// ---------------------------------------------------------------------------
// SimVP Decoder, round 9: conv wave-mapping restructured for B-frag reuse.
// Each wave: 1 output row x 64 oc (4 MFMA oc-slices) -> per K-step ONE
// ds_read_b128 feeds FOUR MFMAs (was 1:1). Block LDS reads 288 -> 72.
// Weights: 24 named v8s per K-chunk (3 chunks of 6 steps), cap 168 VGPR.
// Stats path (R8, proven): block LDS reduce -> slot-spread atomics.
// Pipeline identical to rounds 4-8 (passed):
//   pad(hid) -> hidP ; conv0+PS -> A ; act1 -> Ap ; conv1 -> Bb ; act2 -> Bp
//   conv2+PS -> Cb ; act3(+enc1) -> Cp ; conv3 -> Db ; readout -> Y
//   feamap -> argx ; nz ; final
// ---------------------------------------------------------------------------

#define DEVFN static __device__ __forceinline__

typedef short v8s __attribute__((ext_vector_type(8)));
typedef float v4f __attribute__((ext_vector_type(4)));

DEVFN float silu_f(float t) { return t / (1.f + __expf(-t)); }

DEVFN ushort f2bf(float x) {
  union { float f; unsigned u; } t; t.f = x;
  unsigned r = t.u + 0x7FFFu + ((t.u >> 16) & 1u);
  return (ushort)(r >> 16);
}

__global__ void zero_k(float* __restrict__ p, int n) {
  int i = blockIdx.x * 256 + threadIdx.x;
  if (i < n) p[i] = 0.f;
}

// ---- weight repack: [OC][64][3][3] f32 -> bf16 [kc=tap*8+ic/8][OC][8] -----
template<int OC>
__global__ void repackw_k(const float* __restrict__ src, ushort* __restrict__ dst) {
  int i = blockIdx.x * 256 + threadIdx.x;
  if (i >= OC * 576) return;
  int oc = i / 576, r = i - oc * 576;      // r = ic*9 + tap
  int ic = r / 9, tap = r - ic * 9;
  int kc = tap * 8 + (ic >> 3), j = ic & 7;
  dst[((size_t)kc * OC + oc) * 8 + j] = f2bf(src[i]);
}

// ---- zero the 1-px border of a padded NHWC bf16 buffer --------------------
template<int HP, int WP>
__global__ void border_k(ushort* __restrict__ outP) {
  int idx = blockIdx.x * 256 + threadIdx.x;
  if (idx >= 16 * HP * WP) return;
  int p = idx % (HP * WP);
  int y = p / WP, x = p - y * WP;
  if (y == 0 || y == HP - 1 || x == 0 || x == WP - 1) {
    uint4 z = {0u, 0u, 0u, 0u};
    uint4* dst = (uint4*)(outP + (size_t)idx * 64);
    #pragma unroll
    for (int k = 0; k < 8; ++k) dst[k] = z;
  }
}

// ---- slot-summed GN stats -> (mean, rstd) ---------------------------------
DEVFN void gn_stats(const float* __restrict__ st, int bg, float N,
                    float& mean, float& rstd) {
  float s = 0.f, q = 0.f;
  #pragma unroll
  for (int sl = 0; sl < 8; ++sl) {
    s += st[sl * 64 + bg * 2 + 0];
    q += st[sl * 64 + bg * 2 + 1];
  }
  float m = s / N;
  mean = m;
  rstd = rsqrtf(q / N - m * m + 1e-5f);
}

// ---- act: NCHW f32 -> padded NHWC bf16 via swizzled LDS transpose ---------
// MODE: 0 copy; 1 GN+SiLU; 2 GN+SiLU + addsrc
template<int HW_TOT, int WOUT, int MODE>
__global__ __launch_bounds__(256)
void act_k(const float* __restrict__ in, const float* __restrict__ st,
           const float* __restrict__ gw, const float* __restrict__ gb,
           const float* __restrict__ addsrc, ushort* __restrict__ outP)
{
  constexpr int HOUT = HW_TOT / WOUT;
  constexpr int WP = WOUT + 2, HP = HOUT + 2;
  __shared__ uint4 sT[256 * 8];            // [pixel][slot], slot = cc ^ (pix&7)
  const int tid = threadIdx.x;
  constexpr int NBLK = (HW_TOT + 255) / 256;
  const int b  = blockIdx.x / NBLK;
  const int p0 = (blockIdx.x - b * NBLK) * 256;
  const int px = p0 + tid;

  float mean[2], rstd[2];
  if (MODE >= 1) {
    const float N = 32.f * HW_TOT;
    #pragma unroll
    for (int g = 0; g < 2; ++g) gn_stats(st, b * 2 + g, N, mean[g], rstd[g]);
  }
  if (px < HW_TOT) {
    const float* ip = in + (size_t)b * 64 * HW_TOT + px;
    #pragma unroll 2
    for (int cc = 0; cc < 8; ++cc) {
      unsigned w[4];
      #pragma unroll
      for (int jp = 0; jp < 4; ++jp) {
        float v0, v1;
        #pragma unroll
        for (int h = 0; h < 2; ++h) {
          int c = cc * 8 + jp * 2 + h;
          float v = ip[(size_t)c * HW_TOT];
          if (MODE >= 1) {
            v = silu_f((v - mean[c >> 5]) * rstd[c >> 5] * gw[c] + gb[c]);
            if (MODE == 2) v += addsrc[(size_t)(b * 64 + c) * HW_TOT + px];
          }
          if (h == 0) v0 = v; else v1 = v;
        }
        w[jp] = (unsigned)f2bf(v0) | ((unsigned)f2bf(v1) << 16);
      }
      uint4 pk = {w[0], w[1], w[2], w[3]};
      sT[tid * 8 + (cc ^ (tid & 7))] = pk;
    }
  }
  __syncthreads();
  const int o = tid & 7, pr = tid >> 3;
  #pragma unroll
  for (int i = 0; i < 8; ++i) {
    int p = i * 32 + pr;
    int gpx = p0 + p;
    if (gpx < HW_TOT) {
      int y = gpx / WOUT, x = gpx - y * WOUT;
      uint4 val = sT[p * 8 + (o ^ (p & 7))];
      *(uint4*)(outP + (((size_t)(b * HP) + y + 1) * WP + (x + 1)) * 64 + o * 8) = val;
    }
  }
}

// ---- MFMA implicit-GEMM 3x3 conv ------------------------------------------
// inP: padded NHWC bf16; wrep: [72][OCT][8] bf16; out: NCHW f32 (post-PS if PSF)
// Wave = 1 output row x 64 oc (4 slices of 16). Per K-step: 1 ds_read_b128
// feeds 4 MFMAs (slices share the B-frag). K in 3 chunks of 6 steps; 24
// named weight v8s live per chunk.

#define WLD(nm, i, s) \
  v8s nm = ((const v8s*)wrep)[(size_t)((i) * 4 + sub) * OCT + oc0 + (s) * 16 + lx];

// B-fragment read: step i for this wave's row. dy=i/6, dx=(i>>1)%3, half=i&1.
#define BRD1(i) __builtin_bit_cast(v8s, sQ[ \
    ((wave + (i) / 6) * LWS + (xb + lx + (((i) >> 1) % 3))) * 8 + \
    (((((i) & 1) * 4 + sub)) ^ ((xb + lx + (((i) >> 1) % 3)) & 7))])

#define KST(i, wa, wb, wc, wd) { \
    v8s b_ = BRD1(i); \
    a0 = __builtin_amdgcn_mfma_f32_16x16x32_bf16(wa, b_, a0, 0, 0, 0); \
    a1 = __builtin_amdgcn_mfma_f32_16x16x32_bf16(wb, b_, a1, 0, 0, 0); \
    a2 = __builtin_amdgcn_mfma_f32_16x16x32_bf16(wc, b_, a2, 0, 0, 0); \
    a3 = __builtin_amdgcn_mfma_f32_16x16x32_bf16(wd, b_, a3, 0, 0, 0); }

#define KCHUNK(k0) { \
    WLD(wa0, (k0) + 0, 0) WLD(wb0, (k0) + 0, 1) WLD(wc0, (k0) + 0, 2) WLD(wd0, (k0) + 0, 3) \
    WLD(wa1, (k0) + 1, 0) WLD(wb1, (k0) + 1, 1) WLD(wc1, (k0) + 1, 2) WLD(wd1, (k0) + 1, 3) \
    WLD(wa2, (k0) + 2, 0) WLD(wb2, (k0) + 2, 1) WLD(wc2, (k0) + 2, 2) WLD(wd2, (k0) + 2, 3) \
    WLD(wa3, (k0) + 3, 0) WLD(wb3, (k0) + 3, 1) WLD(wc3, (k0) + 3, 2) WLD(wd3, (k0) + 3, 3) \
    WLD(wa4, (k0) + 4, 0) WLD(wb4, (k0) + 4, 1) WLD(wc4, (k0) + 4, 2) WLD(wd4, (k0) + 4, 3) \
    WLD(wa5, (k0) + 5, 0) WLD(wb5, (k0) + 5, 1) WLD(wc5, (k0) + 5, 2) WLD(wd5, (k0) + 5, 3) \
    KST((k0) + 0, wa0, wb0, wc0, wd0) \
    KST((k0) + 1, wa1, wb1, wc1, wd1) \
    KST((k0) + 2, wa2, wb2, wc2, wd2) \
    KST((k0) + 3, wa3, wb3, wc3, wd3) \
    KST((k0) + 4, wa4, wb4, wc4, wd4) \
    KST((k0) + 5, wa5, wb5, wc5, wd5) \
  }

#define STOREACC(a, s, sp, qp) { \
    if (!PSF) { \
      _Pragma("unroll") \
      for (int j = 0; j < 4; ++j) { \
        int oc = oc0 + (s) * 16 + sub * 4 + j; \
        out[((size_t)(b * OCT + oc) * HIN + y) * WIN + x] = a[j]; \
      } \
    } else { \
      _Pragma("unroll") \
      for (int j = 0; j < 4; ++j) { \
        int oc = oc0 + (s) * 16 + sub * 4 + j; \
        int c = oc >> 2, rr = (oc >> 1) & 1, ss = oc & 1; \
        out[((size_t)(b * 64 + c) * (2 * HIN) + (2 * y + rr)) * (2 * WIN) \
            + (2 * x + ss)] = a[j]; \
      } \
    } \
    _Pragma("unroll") \
    for (int j = 0; j < 4; ++j) { sp += a[j]; qp += a[j] * a[j]; } }

template<int HIN, int WIN, int WT, int NG, int OCT, bool PSF>
__global__ __launch_bounds__(256, 3)
void convm_k(const uint4* __restrict__ inP, const ushort* __restrict__ wrep,
             const float* __restrict__ bias, float* __restrict__ out,
             float* __restrict__ stp)
{
  constexpr int TH = 4;                    // 4 waves x 1 row
  constexpr int HP = HIN + 2, WP = WIN + 2;
  constexpr int LH = TH + 2, LW = WT + 2;
  constexpr int NOCB = OCT / 64;
  constexpr int LRD = (NG * 16 + 2 > LW) ? (NG * 16 + 2) : LW;
  constexpr int LWS = (LRD + 7) & ~7;      // multiple of 8: (pix&7)==(col&7)
  constexpr int NCHUNK = LH * LWS * 8;
  __shared__ uint4 sQ[NCHUNK];
  __shared__ float red[4][4];

  const int tid  = threadIdx.x;
  const int lane = tid & 63;
  const int wave = tid >> 6;               // row within tile
  const int sub  = lane >> 4;
  const int lx   = lane & 15;
  const int b    = blockIdx.y / NOCB;
  const int ocb  = blockIdx.y - b * NOCB;
  constexpr int NTX = WIN / WT;
  const int tx   = blockIdx.x % NTX;
  const int tyy  = blockIdx.x / NTX;
  const int x0   = tx * WT;
  const int y0   = tyy * TH;
  const int oc0  = ocb * 64;               // block's 64-oc slice

  // staging: LINEAR global reads, swizzle on LDS write addr
  const uint4* gsrc = inP + ((size_t)(b * HP + y0) * WP + x0) * 8;
  for (int q = tid; q < NCHUNK; q += 256) {
    int p = q >> 3, cc = q & 7;
    int r = p / LWS, cx = p - r * LWS;
    uint4 v = gsrc[((size_t)r * WP + cx) * 8 + cc];
    sQ[p * 8 + (cc ^ (cx & 7))] = v;
  }

  const v4f binit0 = *(const v4f*)&bias[oc0 + 0 * 16 + sub * 4];
  const v4f binit1 = *(const v4f*)&bias[oc0 + 1 * 16 + sub * 4];
  const v4f binit2 = *(const v4f*)&bias[oc0 + 2 * 16 + sub * 4];
  const v4f binit3 = *(const v4f*)&bias[oc0 + 3 * 16 + sub * 4];

  __syncthreads();

  float sA = 0.f, qA = 0.f, sB = 0.f, qB = 0.f;
  const int y = y0 + wave;

  for (int xg = 0; xg < NG; ++xg) {
    const int xb = xg * 16;
    v4f a0 = binit0, a1 = binit1, a2 = binit2, a3 = binit3;

    KCHUNK(0)
    KCHUNK(6)
    KCHUNK(12)

    const int x = x0 + xb + lx;
    if ((NG * 16 == WT) || (x < WIN)) {
      STOREACC(a0, 0, sA, qA)
      STOREACC(a1, 1, sA, qA)
      STOREACC(a2, 2, sB, qB)
      STOREACC(a3, 3, sB, qB)
    }
  }

  // GroupNorm stats: slices 0-1 = oc [oc0,oc0+32) ; slices 2-3 = next 32.
  #pragma unroll
  for (int o = 32; o >= 1; o >>= 1) {
    sA += __shfl_down(sA, o); qA += __shfl_down(qA, o);
    sB += __shfl_down(sB, o); qB += __shfl_down(qB, o);
  }
  if (lane == 0) {
    red[wave][0] = sA; red[wave][1] = qA; red[wave][2] = sB; red[wave][3] = qB;
  }
  __syncthreads();
  if (tid == 0) {
    float s0 = red[0][0] + red[1][0] + red[2][0] + red[3][0];
    float q0 = red[0][1] + red[1][1] + red[2][1] + red[3][1];
    float s1 = red[0][2] + red[1][2] + red[2][2] + red[3][2];
    float q1 = red[0][3] + red[1][3] + red[2][3] + red[3][3];
    float* basep = stp + (blockIdx.x & 7) * 64;
    if (PSF) {
      int g = ocb >> 1;                    // post-PS group of this 64-oc slice
      atomicAdd(&basep[(b * 2 + g) * 2 + 0], s0 + s1);
      atomicAdd(&basep[(b * 2 + g) * 2 + 1], q0 + q1);
    } else {
      atomicAdd(&basep[(b * 2 + 0) * 2 + 0], s0);
      atomicAdd(&basep[(b * 2 + 0) * 2 + 1], q0);
      atomicAdd(&basep[(b * 2 + 1) * 2 + 0], s1);
      atomicAdd(&basep[(b * 2 + 1) * 2 + 1], q1);
    }
  }
}

// ---- readout: Y[b,o,pix] = rb[o] + sum_c GN_SiLU(D)[b,c,pix] * rw[o,c] ----
__global__ void readout_k(const float* __restrict__ D, const float* __restrict__ st,
                          const float* __restrict__ gw, const float* __restrict__ gb,
                          const float* __restrict__ rw, const float* __restrict__ rb,
                          float* __restrict__ Y)
{
  int idx = blockIdx.x * 256 + threadIdx.x;
  if (idx >= 16 * 25600) return;
  int b = idx / 25600, pix = idx - b * 25600;
  const float N = 32.f * 25600.f;
  float mean[2], rstd[2];
  #pragma unroll
  for (int g = 0; g < 2; ++g) gn_stats(st, b * 2 + g, N, mean[g], rstd[g]);
  float a0 = rb[0], a1 = rb[1], a2 = rb[2];
  const float* dp = D + (size_t)(b * 64) * 25600 + pix;
  #pragma unroll 4
  for (int c = 0; c < 64; ++c) {
    float x = dp[(size_t)c * 25600];
    float t = (x - mean[c >> 5]) * rstd[c >> 5] * gw[c] + gb[c];
    float v = silu_f(t);
    a0 = fmaf(v, rw[c], a0);
    a1 = fmaf(v, rw[64 + c], a1);
    a2 = fmaf(v, rw[128 + c], a2);
  }
  Y[(size_t)(b * 3 + 0) * 25600 + pix] = a0;
  Y[(size_t)(b * 3 + 1) * 25600 + pix] = a1;
  Y[(size_t)(b * 3 + 2) * 25600 + pix] = a2;
}

// ---- feamap: argx = conv(Y, fw, stride 4)/16, first 3 channels ------------
__global__ void feamap_k(const float* __restrict__ Y, const float* __restrict__ fw,
                         float* __restrict__ argx)
{
  int idx = blockIdx.x * 256 + threadIdx.x;
  if (idx >= 16 * 3 * 1600) return;
  int b  = idx / (3 * 1600);
  int o  = (idx / 1600) % 3;
  int ij = idx % 1600;
  int i = ij / 40, j = ij - i * 40;
  float s = 0.f;
  #pragma unroll
  for (int c = 0; c < 3; ++c)
    #pragma unroll
    for (int u = 0; u < 4; ++u)
      #pragma unroll
      for (int v = 0; v < 4; ++v)
        s += Y[((size_t)(b * 3 + c) * 160 + (4 * i + u)) * 160 + (4 * j + v)]
             * fw[((o * 3 + c) * 4 + u) * 4 + v];
  argx[idx] = s * (1.f / 16.f);
}

__global__ void nz_k(const float* __restrict__ attn, float* __restrict__ nzinv) {
  int idx = blockIdx.x * 256 + threadIdx.x;
  if (idx >= 16 * 3 * 256) return;
  const float* p = attn + (size_t)idx * 16;
  int c = 0;
  #pragma unroll
  for (int k = 0; k < 16; ++k) c += (p[k] != 0.f);
  nzinv[idx] = 1.f / ((float)c + 1e-5f);
}

__global__ void final_k(const float* __restrict__ Y, const float* __restrict__ attn,
                        const float* __restrict__ nzinv, const float* __restrict__ argx,
                        float* __restrict__ out)
{
  int idx = blockIdx.x * 256 + threadIdx.x;
  if (idx >= 16 * 3 * 25600) return;
  int bc  = idx / 25600;
  int pix = idx - bc * 25600;
  int y = pix / 160, x = pix - y * 160;
  int l  = (y / 10) * 16 + (x / 10);
  int pi = y % 10,  pj = x % 10;
  const float* ar = attn + ((size_t)bc * 256 + l) * 16;
  const float* ax = argx + (size_t)bc * 1600;
  float inv = nzinv[bc * 256 + l];
  float corr = 0.f;
  #pragma unroll
  for (int k = 0; k < 16; ++k)
    corr += ar[k] * ax[((k >> 2) * 10 + pi) * 40 + ((k & 3) * 10 + pj)];
  float yv = Y[idx];
  out[idx] = yv * (1.f + corr * inv);
}

// ---------------------------------------------------------------------------
extern "C" void kernel_launch(void* const* d_in, const int* in_sizes, int n_in,
                              void* d_out, int out_size, void* d_ws, size_t ws_size,
                              hipStream_t stream)
{
  const float* attn = (const float*)d_in[0];
  const float* hid  = (const float*)d_in[1];
  const float* enc1 = (const float*)d_in[2];
  const float* d0w  = (const float*)d_in[3];
  const float* d0b  = (const float*)d_in[4];
  const float* d0gw = (const float*)d_in[5];
  const float* d0gb = (const float*)d_in[6];
  const float* d1w  = (const float*)d_in[7];
  const float* d1b  = (const float*)d_in[8];
  const float* d1gw = (const float*)d_in[9];
  const float* d1gb = (const float*)d_in[10];
  const float* d2w  = (const float*)d_in[11];
  const float* d2b  = (const float*)d_in[12];
  const float* d2gw = (const float*)d_in[13];
  const float* d2gb = (const float*)d_in[14];
  const float* d3w  = (const float*)d_in[15];
  const float* d3b  = (const float*)d_in[16];
  const float* d3gw = (const float*)d_in[17];
  const float* d3gb = (const float*)d_in[18];
  const float* rw   = (const float*)d_in[19];
  const float* rb   = (const float*)d_in[20];
  const float* fw   = (const float*)d_in[21];

  float* ws = (float*)d_ws;
  size_t o = 0;
  float* bufA  = ws + o; o += (size_t)16 * 64 * 80 * 80;       // A / Bb / Y+argx+nzv
  float* bufAp = ws + o; o += (size_t)16 * 82 * 82 * 64 / 2;   // Ap / Bp  (bf16)
  float* bufC  = ws + o; o += (size_t)16 * 64 * 160 * 160;     // Cb / Db
  float* bufCp = ws + o; o += (size_t)16 * 162 * 162 * 64 / 2; // Cp (bf16)
  float* hidPf = ws + o; o += (size_t)16 * 42 * 42 * 64 / 2;   // hidP (bf16)
  float* st    = ws + o; o += 4 * 512;                         // slotted stats
  float* w0f   = ws + o; o += (size_t)72 * 256 * 8 / 2;
  float* w1f   = ws + o; o += (size_t)72 * 64 * 8 / 2;
  float* w2f   = ws + o; o += (size_t)72 * 256 * 8 / 2;
  float* w3f   = ws + o; o += (size_t)72 * 64 * 8 / 2;

  float*  A    = bufA;
  float*  Bb   = bufA;
  ushort* Ap   = (ushort*)bufAp;
  ushort* Bp   = (ushort*)bufAp;
  float*  Cb   = bufC;
  float*  Db   = bufC;
  ushort* Cp   = (ushort*)bufCp;
  ushort* hidP = (ushort*)hidPf;
  float*  Y    = bufA;
  float*  argx = bufA + (size_t)16 * 3 * 25600;
  float*  nzv  = argx + (size_t)16 * 3 * 1600;
  ushort* wr0  = (ushort*)w0f;
  ushort* wr1  = (ushort*)w1f;
  ushort* wr2  = (ushort*)w2f;
  ushort* wr3  = (ushort*)w3f;

  zero_k<<<8, 256, 0, stream>>>(st, 4 * 512);

  repackw_k<256><<<(256 * 576 + 255) / 256, 256, 0, stream>>>(d0w, wr0);
  repackw_k<64><<<(64 * 576 + 255) / 256, 256, 0, stream>>>(d1w, wr1);
  repackw_k<256><<<(256 * 576 + 255) / 256, 256, 0, stream>>>(d2w, wr2);
  repackw_k<64><<<(64 * 576 + 255) / 256, 256, 0, stream>>>(d3w, wr3);

  // borders (zeroed every call; act kernels write interiors only)
  border_k<42, 42><<<(16 * 42 * 42 + 255) / 256, 256, 0, stream>>>(hidP);
  border_k<82, 82><<<(16 * 82 * 82 + 255) / 256, 256, 0, stream>>>(Ap);
  border_k<162, 162><<<(16 * 162 * 162 + 255) / 256, 256, 0, stream>>>(Cp);

  // pad hid -> hidP (NHWC bf16)
  act_k<1600, 40, 0><<<16 * 7, 256, 0, stream>>>(hid, nullptr, nullptr, nullptr,
                                                 nullptr, hidP);

  // stage 0: conv(hidP)+PS -> A, stats st0   (40x40, OC=256, ragged NG=3)
  convm_k<40, 40, 40, 3, 256, true>
    <<<dim3(10, 16 * 4), 256, 0, stream>>>((const uint4*)hidP, wr0, d0b, A,
                                           st + 0 * 512);

  // act1 -> Ap
  act_k<6400, 80, 1><<<16 * 25, 256, 0, stream>>>(A, st + 0 * 512, d0gw, d0gb,
                                                  nullptr, Ap);
  // stage 1: conv(Ap) -> Bb, stats st1
  convm_k<80, 80, 16, 1, 64, false>
    <<<dim3(100, 16), 256, 0, stream>>>((const uint4*)Ap, wr1, d1b, Bb,
                                        st + 1 * 512);

  // act2 -> Bp
  act_k<6400, 80, 1><<<16 * 25, 256, 0, stream>>>(Bb, st + 1 * 512, d1gw, d1gb,
                                                  nullptr, Bp);
  // stage 2: conv(Bp)+PS -> Cb, stats st2
  convm_k<80, 80, 16, 1, 256, true>
    <<<dim3(100, 16 * 4), 256, 0, stream>>>((const uint4*)Bp, wr2, d2b, Cb,
                                            st + 2 * 512);

  // act3 (+enc1) -> Cp
  act_k<25600, 160, 2><<<16 * 100, 256, 0, stream>>>(Cb, st + 2 * 512, d2gw,
                                                     d2gb, enc1, Cp);
  // stage 3: conv(Cp) -> Db, stats st3
  convm_k<160, 160, 16, 1, 64, false>
    <<<dim3(400, 16), 256, 0, stream>>>((const uint4*)Cp, wr3, d3b, Db,
                                        st + 3 * 512);

  // readout -> Y
  readout_k<<<(16 * 25600 + 255) / 256, 256, 0, stream>>>(Db, st + 3 * 512,
      d3gw, d3gb, rw, rb, Y);

  feamap_k<<<(16 * 3 * 1600 + 255) / 256, 256, 0, stream>>>(Y, fw, argx);
  nz_k<<<(16 * 3 * 256 + 255) / 256, 256, 0, stream>>>(attn, nzv);
  final_k<<<(16 * 3 * 25600 + 255) / 256, 256, 0, stream>>>(Y, attn, nzv, argx,
      (float*)d_out);
}

// Round 10
// 297.604 us; speedup vs baseline: 1.1744x; 1.1744x over previous
//
#include <hip/hip_runtime.h>

// ---------------------------------------------------------------------------
// SimVP Decoder, round 10: conv with block-resident weights + row pipeline.
// R9 post-mortem: compiler streamed weights from L2 per wave (VGPR=32) ->
// 1.84 GB L2 traffic per big conv = the real bottleneck since R4.
// Now: block = 16 rows x 16 px x 64 oc, 8-iter row loop, double-buffered LDS
// input tiles; wave = 1 row x 32 oc with 36 NAMED weight v8s (144 VGPR)
// hoisted once per block. 1 ds_read_b128 : 2 MFMA. Async stage split
// (loads before compute, ds_write after). Stats path per R8 (proven).
// Pipeline identical to rounds 4-9 (passed).
// ---------------------------------------------------------------------------

#define DEVFN static __device__ __forceinline__

typedef short v8s __attribute__((ext_vector_type(8)));
typedef float v4f __attribute__((ext_vector_type(4)));

DEVFN float silu_f(float t) { return t / (1.f + __expf(-t)); }

DEVFN ushort f2bf(float x) {
  union { float f; unsigned u; } t; t.f = x;
  unsigned r = t.u + 0x7FFFu + ((t.u >> 16) & 1u);
  return (ushort)(r >> 16);
}

__global__ void zero_k(float* __restrict__ p, int n) {
  int i = blockIdx.x * 256 + threadIdx.x;
  if (i < n) p[i] = 0.f;
}

// ---- weight repack: [OC][64][3][3] f32 -> bf16 [kc=tap*8+ic/8][OC][8] -----
template<int OC>
__global__ void repackw_k(const float* __restrict__ src, ushort* __restrict__ dst) {
  int i = blockIdx.x * 256 + threadIdx.x;
  if (i >= OC * 576) return;
  int oc = i / 576, r = i - oc * 576;      // r = ic*9 + tap
  int ic = r / 9, tap = r - ic * 9;
  int kc = tap * 8 + (ic >> 3), j = ic & 7;
  dst[((size_t)kc * OC + oc) * 8 + j] = f2bf(src[i]);
}

// ---- zero the 1-px border of a padded NHWC bf16 buffer --------------------
template<int HP, int WP>
__global__ void border_k(ushort* __restrict__ outP) {
  int idx = blockIdx.x * 256 + threadIdx.x;
  if (idx >= 16 * HP * WP) return;
  int p = idx % (HP * WP);
  int y = p / WP, x = p - y * WP;
  if (y == 0 || y == HP - 1 || x == 0 || x == WP - 1) {
    uint4 z = {0u, 0u, 0u, 0u};
    uint4* dst = (uint4*)(outP + (size_t)idx * 64);
    #pragma unroll
    for (int k = 0; k < 8; ++k) dst[k] = z;
  }
}

// ---- slot-summed GN stats -> (mean, rstd) ---------------------------------
DEVFN void gn_stats(const float* __restrict__ st, int bg, float N,
                    float& mean, float& rstd) {
  float s = 0.f, q = 0.f;
  #pragma unroll
  for (int sl = 0; sl < 8; ++sl) {
    s += st[sl * 64 + bg * 2 + 0];
    q += st[sl * 64 + bg * 2 + 1];
  }
  float m = s / N;
  mean = m;
  rstd = rsqrtf(q / N - m * m + 1e-5f);
}

// ---- act: NCHW f32 -> padded NHWC bf16 via swizzled LDS transpose ---------
// MODE: 0 copy; 1 GN+SiLU; 2 GN+SiLU + addsrc
template<int HW_TOT, int WOUT, int MODE>
__global__ __launch_bounds__(256)
void act_k(const float* __restrict__ in, const float* __restrict__ st,
           const float* __restrict__ gw, const float* __restrict__ gb,
           const float* __restrict__ addsrc, ushort* __restrict__ outP)
{
  constexpr int HOUT = HW_TOT / WOUT;
  constexpr int WP = WOUT + 2, HP = HOUT + 2;
  __shared__ uint4 sT[256 * 8];            // [pixel][slot], slot = cc ^ (pix&7)
  const int tid = threadIdx.x;
  constexpr int NBLK = (HW_TOT + 255) / 256;
  const int b  = blockIdx.x / NBLK;
  const int p0 = (blockIdx.x - b * NBLK) * 256;
  const int px = p0 + tid;

  float mean[2], rstd[2];
  if (MODE >= 1) {
    const float N = 32.f * HW_TOT;
    #pragma unroll
    for (int g = 0; g < 2; ++g) gn_stats(st, b * 2 + g, N, mean[g], rstd[g]);
  }
  if (px < HW_TOT) {
    const float* ip = in + (size_t)b * 64 * HW_TOT + px;
    #pragma unroll 2
    for (int cc = 0; cc < 8; ++cc) {
      unsigned w[4];
      #pragma unroll
      for (int jp = 0; jp < 4; ++jp) {
        float v0, v1;
        #pragma unroll
        for (int h = 0; h < 2; ++h) {
          int c = cc * 8 + jp * 2 + h;
          float v = ip[(size_t)c * HW_TOT];
          if (MODE >= 1) {
            v = silu_f((v - mean[c >> 5]) * rstd[c >> 5] * gw[c] + gb[c]);
            if (MODE == 2) v += addsrc[(size_t)(b * 64 + c) * HW_TOT + px];
          }
          if (h == 0) v0 = v; else v1 = v;
        }
        w[jp] = (unsigned)f2bf(v0) | ((unsigned)f2bf(v1) << 16);
      }
      uint4 pk = {w[0], w[1], w[2], w[3]};
      sT[tid * 8 + (cc ^ (tid & 7))] = pk;
    }
  }
  __syncthreads();
  const int o = tid & 7, pr = tid >> 3;
  #pragma unroll
  for (int i = 0; i < 8; ++i) {
    int p = i * 32 + pr;
    int gpx = p0 + p;
    if (gpx < HW_TOT) {
      int y = gpx / WOUT, x = gpx - y * WOUT;
      uint4 val = sT[p * 8 + (o ^ (p & 7))];
      *(uint4*)(outP + (((size_t)(b * HP) + y + 1) * WP + (x + 1)) * 64 + o * 8) = val;
    }
  }
}

// ---- MFMA implicit-GEMM 3x3 conv, row-pipelined ---------------------------
// Block: RPB rows x WT px x 64 oc. 4 waves: wave = 1 row x 32 oc
// (wrow = wave>>1 in {0,1}, ochalf = wave&1). RPB/2 iterations of 2 rows,
// double-buffered LDS input tile (LH=4 padded rows).
// Weights: 36 named v8s per wave (18 K-steps x 2 oc-slices), loaded once.

#define FE18(M) M(0) M(1) M(2) M(3) M(4) M(5) M(6) M(7) M(8) M(9) M(10) \
                M(11) M(12) M(13) M(14) M(15) M(16) M(17)

#define WDL(t) \
  v8s Wa##t = ((const v8s*)wrep)[(size_t)((t) * 4 + sub) * OCT + ocbase + lx]; \
  v8s Wb##t = ((const v8s*)wrep)[(size_t)((t) * 4 + sub) * OCT + ocbase + 16 + lx];

// step t: tap = t>>1 (dy=t/6, dx=(t>>1)%3), icc-half = t&1
#define KST(t) { \
    const int col_ = xb + lx + (((t) >> 1) % 3); \
    v8s b_ = __builtin_bit_cast(v8s, sb[((wrow + (t) / 6) * LWS + col_) * 8 + \
                                        (((((t) & 1) * 4 + sub)) ^ (col_ & 7))]); \
    a0 = __builtin_amdgcn_mfma_f32_16x16x32_bf16(Wa##t, b_, a0, 0, 0, 0); \
    a1 = __builtin_amdgcn_mfma_f32_16x16x32_bf16(Wb##t, b_, a1, 0, 0, 0); }

template<int HIN, int WIN, int WT, int NG, int RPB, int OCT, bool PSF, int MW>
__global__ __launch_bounds__(256, MW)
void convm_k(const uint4* __restrict__ inP, const ushort* __restrict__ wrep,
             const float* __restrict__ bias, float* __restrict__ out,
             float* __restrict__ stp)
{
  constexpr int HP = HIN + 2, WP = WIN + 2;
  constexpr int LH = 4, LW = WT + 2;
  constexpr int NOCB = OCT / 64;
  constexpr int LRD = (NG * 16 + 2 > LW) ? (NG * 16 + 2) : LW;
  constexpr int LWS = (LRD + 7) & ~7;      // multiple of 8: (pix&7)==(col&7)
  constexpr int NCHUNK = LH * LWS * 8;     // per buffer (multiple of 256)
  constexpr int STK = NCHUNK / 256;
  constexpr int NIT = RPB / 2;
  __shared__ uint4 sQ[2 * NCHUNK];
  __shared__ float red[4][2];

  const int tid  = threadIdx.x;
  const int lane = tid & 63;
  const int wave = tid >> 6;
  const int sub  = lane >> 4;
  const int lx   = lane & 15;
  const int wrow = wave >> 1;              // row within 2-row iter
  const int b    = blockIdx.y / NOCB;
  const int ocb  = blockIdx.y - b * NOCB;
  constexpr int NTX = WIN / WT;
  const int tx    = blockIdx.x % NTX;
  const int ych   = blockIdx.x / NTX;
  const int x0    = tx * WT;
  const int ybase = ych * RPB;
  const int ocbase = ocb * 64 + (wave & 1) * 32;

  // ---- hoisted weights: 36 named v8s (loaded once; overlap with staging)
  FE18(WDL)

  const v4f bi0 = *(const v4f*)&bias[ocbase + sub * 4];
  const v4f bi1 = *(const v4f*)&bias[ocbase + 16 + sub * 4];

  // ---- per-thread staging coords (static, registers)
  int gidx_[STK], pdst_[STK];
  #pragma unroll
  for (int k = 0; k < STK; ++k) {
    int q = tid + k * 256;
    int p = q >> 3, cc = q & 7;
    int r = p / LWS, cx = p - r * LWS;
    gidx_[k] = (r * WP + cx) * 8 + cc;
    pdst_[k] = p * 8 + (cc ^ (cx & 7));
  }

  const uint4* gbase = inP + ((size_t)(b * HP + ybase) * WP + x0) * 8;

  // prologue: stage iter 0 into buf 0
  #pragma unroll
  for (int k = 0; k < STK; ++k) sQ[pdst_[k]] = gbase[gidx_[k]];
  __syncthreads();

  float sA = 0.f, qA = 0.f;

  for (int it = 0; it < NIT; ++it) {
    const uint4* sb = sQ + (it & 1) * NCHUNK;
    uint4* so = sQ + ((it + 1) & 1) * NCHUNK;
    const bool more = (it + 1 < NIT);

    uint4 stg[STK];
    if (more) {
      const uint4* gs = gbase + (size_t)(it + 1) * 2 * WP * 8;
      #pragma unroll
      for (int k = 0; k < STK; ++k) stg[k] = gs[gidx_[k]];
    }

    const int y = ybase + it * 2 + wrow;
    for (int xg = 0; xg < NG; ++xg) {
      const int xb = xg * 16;
      v4f a0 = bi0, a1 = bi1;
      FE18(KST)
      const int x = x0 + xb + lx;
      if ((NG * 16 == WT) || (x < WIN)) {
        #pragma unroll
        for (int s = 0; s < 2; ++s) {
          const v4f a = s ? a1 : a0;
          if (!PSF) {
            #pragma unroll
            for (int j = 0; j < 4; ++j) {
              int oc = ocbase + s * 16 + sub * 4 + j;
              out[((size_t)(b * OCT + oc) * HIN + y) * WIN + x] = a[j];
            }
          } else {
            #pragma unroll
            for (int j = 0; j < 4; ++j) {
              int oc = ocbase + s * 16 + sub * 4 + j;
              int c = oc >> 2, rr = (oc >> 1) & 1, ss = oc & 1;
              out[((size_t)(b * 64 + c) * (2 * HIN) + (2 * y + rr)) * (2 * WIN)
                  + (2 * x + ss)] = a[j];
            }
          }
          #pragma unroll
          for (int j = 0; j < 4; ++j) { sA += a[j]; qA += a[j] * a[j]; }
        }
      }
    }

    if (more) {
      #pragma unroll
      for (int k = 0; k < STK; ++k) so[pdst_[k]] = stg[k];
    }
    __syncthreads();
  }

  // ---- GroupNorm stats: wave covers 32 oc = one group (non-PS) -----------
  #pragma unroll
  for (int o = 32; o >= 1; o >>= 1) {
    sA += __shfl_down(sA, o);
    qA += __shfl_down(qA, o);
  }
  if (lane == 0) { red[wave][0] = sA; red[wave][1] = qA; }
  __syncthreads();
  if (tid == 0) {
    float* basep = stp + (blockIdx.x & 7) * 64;
    if (PSF) {
      int g = ocb >> 1;
      atomicAdd(&basep[(b * 2 + g) * 2 + 0],
                red[0][0] + red[1][0] + red[2][0] + red[3][0]);
      atomicAdd(&basep[(b * 2 + g) * 2 + 1],
                red[0][1] + red[1][1] + red[2][1] + red[3][1]);
    } else {
      atomicAdd(&basep[(b * 2 + 0) * 2 + 0], red[0][0] + red[2][0]);
      atomicAdd(&basep[(b * 2 + 0) * 2 + 1], red[0][1] + red[2][1]);
      atomicAdd(&basep[(b * 2 + 1) * 2 + 0], red[1][0] + red[3][0]);
      atomicAdd(&basep[(b * 2 + 1) * 2 + 1], red[1][1] + red[3][1]);
    }
  }
}

// ---- readout: Y[b,o,pix] = rb[o] + sum_c GN_SiLU(D)[b,c,pix] * rw[o,c] ----
__global__ void readout_k(const float* __restrict__ D, const float* __restrict__ st,
                          const float* __restrict__ gw, const float* __restrict__ gb,
                          const float* __restrict__ rw, const float* __restrict__ rb,
                          float* __restrict__ Y)
{
  int idx = blockIdx.x * 256 + threadIdx.x;
  if (idx >= 16 * 25600) return;
  int b = idx / 25600, pix = idx - b * 25600;
  const float N = 32.f * 25600.f;
  float mean[2], rstd[2];
  #pragma unroll
  for (int g = 0; g < 2; ++g) gn_stats(st, b * 2 + g, N, mean[g], rstd[g]);
  float a0 = rb[0], a1 = rb[1], a2 = rb[2];
  const float* dp = D + (size_t)(b * 64) * 25600 + pix;
  #pragma unroll 4
  for (int c = 0; c < 64; ++c) {
    float x = dp[(size_t)c * 25600];
    float t = (x - mean[c >> 5]) * rstd[c >> 5] * gw[c] + gb[c];
    float v = silu_f(t);
    a0 = fmaf(v, rw[c], a0);
    a1 = fmaf(v, rw[64 + c], a1);
    a2 = fmaf(v, rw[128 + c], a2);
  }
  Y[(size_t)(b * 3 + 0) * 25600 + pix] = a0;
  Y[(size_t)(b * 3 + 1) * 25600 + pix] = a1;
  Y[(size_t)(b * 3 + 2) * 25600 + pix] = a2;
}

// ---- feamap: argx = conv(Y, fw, stride 4)/16, first 3 channels ------------
__global__ void feamap_k(const float* __restrict__ Y, const float* __restrict__ fw,
                         float* __restrict__ argx)
{
  int idx = blockIdx.x * 256 + threadIdx.x;
  if (idx >= 16 * 3 * 1600) return;
  int b  = idx / (3 * 1600);
  int o  = (idx / 1600) % 3;
  int ij = idx % 1600;
  int i = ij / 40, j = ij - i * 40;
  float s = 0.f;
  #pragma unroll
  for (int c = 0; c < 3; ++c)
    #pragma unroll
    for (int u = 0; u < 4; ++u)
      #pragma unroll
      for (int v = 0; v < 4; ++v)
        s += Y[((size_t)(b * 3 + c) * 160 + (4 * i + u)) * 160 + (4 * j + v)]
             * fw[((o * 3 + c) * 4 + u) * 4 + v];
  argx[idx] = s * (1.f / 16.f);
}

__global__ void nz_k(const float* __restrict__ attn, float* __restrict__ nzinv) {
  int idx = blockIdx.x * 256 + threadIdx.x;
  if (idx >= 16 * 3 * 256) return;
  const float* p = attn + (size_t)idx * 16;
  int c = 0;
  #pragma unroll
  for (int k = 0; k < 16; ++k) c += (p[k] != 0.f);
  nzinv[idx] = 1.f / ((float)c + 1e-5f);
}

__global__ void final_k(const float* __restrict__ Y, const float* __restrict__ attn,
                        const float* __restrict__ nzinv, const float* __restrict__ argx,
                        float* __restrict__ out)
{
  int idx = blockIdx.x * 256 + threadIdx.x;
  if (idx >= 16 * 3 * 25600) return;
  int bc  = idx / 25600;
  int pix = idx - bc * 25600;
  int y = pix / 160, x = pix - y * 160;
  int l  = (y / 10) * 16 + (x / 10);
  int pi = y % 10,  pj = x % 10;
  const float* ar = attn + ((size_t)bc * 256 + l) * 16;
  const float* ax = argx + (size_t)bc * 1600;
  float inv = nzinv[bc * 256 + l];
  float corr = 0.f;
  #pragma unroll
  for (int k = 0; k < 16; ++k)
    corr += ar[k] * ax[((k >> 2) * 10 + pi) * 40 + ((k & 3) * 10 + pj)];
  float yv = Y[idx];
  out[idx] = yv * (1.f + corr * inv);
}

// ---------------------------------------------------------------------------
extern "C" void kernel_launch(void* const* d_in, const int* in_sizes, int n_in,
                              void* d_out, int out_size, void* d_ws, size_t ws_size,
                              hipStream_t stream)
{
  const float* attn = (const float*)d_in[0];
  const float* hid  = (const float*)d_in[1];
  const float* enc1 = (const float*)d_in[2];
  const float* d0w  = (const float*)d_in[3];
  const float* d0b  = (const float*)d_in[4];
  const float* d0gw = (const float*)d_in[5];
  const float* d0gb = (const float*)d_in[6];
  const float* d1w  = (const float*)d_in[7];
  const float* d1b  = (const float*)d_in[8];
  const float* d1gw = (const float*)d_in[9];
  const float* d1gb = (const float*)d_in[10];
  const float* d2w  = (const float*)d_in[11];
  const float* d2b  = (const float*)d_in[12];
  const float* d2gw = (const float*)d_in[13];
  const float* d2gb = (const float*)d_in[14];
  const float* d3w  = (const float*)d_in[15];
  const float* d3b  = (const float*)d_in[16];
  const float* d3gw = (const float*)d_in[17];
  const float* d3gb = (const float*)d_in[18];
  const float* rw   = (const float*)d_in[19];
  const float* rb   = (const float*)d_in[20];
  const float* fw   = (const float*)d_in[21];

  float* ws = (float*)d_ws;
  size_t o = 0;
  float* bufA  = ws + o; o += (size_t)16 * 64 * 80 * 80;       // A / Bb / Y+argx+nzv
  float* bufAp = ws + o; o += (size_t)16 * 82 * 82 * 64 / 2;   // Ap / Bp  (bf16)
  float* bufC  = ws + o; o += (size_t)16 * 64 * 160 * 160;     // Cb / Db
  float* bufCp = ws + o; o += (size_t)16 * 162 * 162 * 64 / 2; // Cp (bf16)
  float* hidPf = ws + o; o += (size_t)16 * 42 * 42 * 64 / 2;   // hidP (bf16)
  float* st    = ws + o; o += 4 * 512;                         // slotted stats
  float* w0f   = ws + o; o += (size_t)72 * 256 * 8 / 2;
  float* w1f   = ws + o; o += (size_t)72 * 64 * 8 / 2;
  float* w2f   = ws + o; o += (size_t)72 * 256 * 8 / 2;
  float* w3f   = ws + o; o += (size_t)72 * 64 * 8 / 2;

  float*  A    = bufA;
  float*  Bb   = bufA;
  ushort* Ap   = (ushort*)bufAp;
  ushort* Bp   = (ushort*)bufAp;
  float*  Cb   = bufC;
  float*  Db   = bufC;
  ushort* Cp   = (ushort*)bufCp;
  ushort* hidP = (ushort*)hidPf;
  float*  Y    = bufA;
  float*  argx = bufA + (size_t)16 * 3 * 25600;
  float*  nzv  = argx + (size_t)16 * 3 * 1600;
  ushort* wr0  = (ushort*)w0f;
  ushort* wr1  = (ushort*)w1f;
  ushort* wr2  = (ushort*)w2f;
  ushort* wr3  = (ushort*)w3f;

  zero_k<<<8, 256, 0, stream>>>(st, 4 * 512);

  repackw_k<256><<<(256 * 576 + 255) / 256, 256, 0, stream>>>(d0w, wr0);
  repackw_k<64><<<(64 * 576 + 255) / 256, 256, 0, stream>>>(d1w, wr1);
  repackw_k<256><<<(256 * 576 + 255) / 256, 256, 0, stream>>>(d2w, wr2);
  repackw_k<64><<<(64 * 576 + 255) / 256, 256, 0, stream>>>(d3w, wr3);

  // borders (zeroed every call; act kernels write interiors only)
  border_k<42, 42><<<(16 * 42 * 42 + 255) / 256, 256, 0, stream>>>(hidP);
  border_k<82, 82><<<(16 * 82 * 82 + 255) / 256, 256, 0, stream>>>(Ap);
  border_k<162, 162><<<(16 * 162 * 162 + 255) / 256, 256, 0, stream>>>(Cp);

  // pad hid -> hidP (NHWC bf16)
  act_k<1600, 40, 0><<<16 * 7, 256, 0, stream>>>(hid, nullptr, nullptr, nullptr,
                                                 nullptr, hidP);

  // stage 0: conv(hidP)+PS -> A, stats st0 (40x40, OC=256, WT=40 NG=3, RPB=8)
  convm_k<40, 40, 40, 3, 8, 256, true, 1>
    <<<dim3(5, 16 * 4), 256, 0, stream>>>((const uint4*)hidP, wr0, d0b, A,
                                          st + 0 * 512);

  // act1 -> Ap
  act_k<6400, 80, 1><<<16 * 25, 256, 0, stream>>>(A, st + 0 * 512, d0gw, d0gb,
                                                  nullptr, Ap);
  // stage 1: conv(Ap) -> Bb, stats st1 (80x80: 5 x-strips x 5 y-chunks)
  convm_k<80, 80, 16, 1, 16, 64, false, 2>
    <<<dim3(25, 16), 256, 0, stream>>>((const uint4*)Ap, wr1, d1b, Bb,
                                       st + 1 * 512);

  // act2 -> Bp
  act_k<6400, 80, 1><<<16 * 25, 256, 0, stream>>>(Bb, st + 1 * 512, d1gw, d1gb,
                                                  nullptr, Bp);
  // stage 2: conv(Bp)+PS -> Cb, stats st2
  convm_k<80, 80, 16, 1, 16, 256, true, 2>
    <<<dim3(25, 16 * 4), 256, 0, stream>>>((const uint4*)Bp, wr2, d2b, Cb,
                                           st + 2 * 512);

  // act3 (+enc1) -> Cp
  act_k<25600, 160, 2><<<16 * 100, 256, 0, stream>>>(Cb, st + 2 * 512, d2gw,
                                                     d2gb, enc1, Cp);
  // stage 3: conv(Cp) -> Db, stats st3 (160x160: 10 x-strips x 10 y-chunks)
  convm_k<160, 160, 16, 1, 16, 64, false, 2>
    <<<dim3(100, 16), 256, 0, stream>>>((const uint4*)Cp, wr3, d3b, Db,
                                        st + 3 * 512);

  // readout -> Y
  readout_k<<<(16 * 25600 + 255) / 256, 256, 0, stream>>>(Db, st + 3 * 512,
      d3gw, d3gb, rw, rb, Y);

  feamap_k<<<(16 * 3 * 1600 + 255) / 256, 256, 0, stream>>>(Y, fw, argx);
  nz_k<<<(16 * 3 * 256 + 255) / 256, 256, 0, stream>>>(attn, nzv);
  final_k<<<(16 * 3 * 25600 + 255) / 256, 256, 0, stream>>>(Y, attn, nzv, argx,
      (float*)d_out);
}

// Round 11
// 268.754 us; speedup vs baseline: 1.3005x; 1.1073x over previous
//
#include <hip/hip_runtime.h>

// ---------------------------------------------------------------------------
// SimVP Decoder, round 11: conv = single-staged row strip + guaranteed
// register-resident weights.
// R10 post-mortem: compiler squeezed VGPR to the 128 boundary (< 144 needed
// for 36 weight v8s) -> per-iteration L2 weight reloads + barrier drains =
// ~3.4k cy/iter. Now: amdgpu_waves_per_eu(2,2) (budget 256, no squeeze),
// stage all RPB+2 rows once (one barrier), barrier-free row-pair loop.
// Stats path per R8 (proven). Pipeline identical to rounds 4-10 (passed).
// ---------------------------------------------------------------------------

#define DEVFN static __device__ __forceinline__

typedef short v8s __attribute__((ext_vector_type(8)));
typedef float v4f __attribute__((ext_vector_type(4)));

DEVFN float silu_f(float t) { return t / (1.f + __expf(-t)); }

DEVFN ushort f2bf(float x) {
  union { float f; unsigned u; } t; t.f = x;
  unsigned r = t.u + 0x7FFFu + ((t.u >> 16) & 1u);
  return (ushort)(r >> 16);
}

__global__ void zero_k(float* __restrict__ p, int n) {
  int i = blockIdx.x * 256 + threadIdx.x;
  if (i < n) p[i] = 0.f;
}

// ---- weight repack: [OC][64][3][3] f32 -> bf16 [kc=tap*8+ic/8][OC][8] -----
template<int OC>
__global__ void repackw_k(const float* __restrict__ src, ushort* __restrict__ dst) {
  int i = blockIdx.x * 256 + threadIdx.x;
  if (i >= OC * 576) return;
  int oc = i / 576, r = i - oc * 576;      // r = ic*9 + tap
  int ic = r / 9, tap = r - ic * 9;
  int kc = tap * 8 + (ic >> 3), j = ic & 7;
  dst[((size_t)kc * OC + oc) * 8 + j] = f2bf(src[i]);
}

// ---- zero the 1-px border of a padded NHWC bf16 buffer --------------------
template<int HP, int WP>
__global__ void border_k(ushort* __restrict__ outP) {
  int idx = blockIdx.x * 256 + threadIdx.x;
  if (idx >= 16 * HP * WP) return;
  int p = idx % (HP * WP);
  int y = p / WP, x = p - y * WP;
  if (y == 0 || y == HP - 1 || x == 0 || x == WP - 1) {
    uint4 z = {0u, 0u, 0u, 0u};
    uint4* dst = (uint4*)(outP + (size_t)idx * 64);
    #pragma unroll
    for (int k = 0; k < 8; ++k) dst[k] = z;
  }
}

// ---- slot-summed GN stats -> (mean, rstd) ---------------------------------
DEVFN void gn_stats(const float* __restrict__ st, int bg, float N,
                    float& mean, float& rstd) {
  float s = 0.f, q = 0.f;
  #pragma unroll
  for (int sl = 0; sl < 8; ++sl) {
    s += st[sl * 64 + bg * 2 + 0];
    q += st[sl * 64 + bg * 2 + 1];
  }
  float m = s / N;
  mean = m;
  rstd = rsqrtf(q / N - m * m + 1e-5f);
}

// ---- act: NCHW f32 -> padded NHWC bf16 via swizzled LDS transpose ---------
// MODE: 0 copy; 1 GN+SiLU; 2 GN+SiLU + addsrc
template<int HW_TOT, int WOUT, int MODE>
__global__ __launch_bounds__(256)
void act_k(const float* __restrict__ in, const float* __restrict__ st,
           const float* __restrict__ gw, const float* __restrict__ gb,
           const float* __restrict__ addsrc, ushort* __restrict__ outP)
{
  constexpr int HOUT = HW_TOT / WOUT;
  constexpr int WP = WOUT + 2, HP = HOUT + 2;
  __shared__ uint4 sT[256 * 8];            // [pixel][slot], slot = cc ^ (pix&7)
  const int tid = threadIdx.x;
  constexpr int NBLK = (HW_TOT + 255) / 256;
  const int b  = blockIdx.x / NBLK;
  const int p0 = (blockIdx.x - b * NBLK) * 256;
  const int px = p0 + tid;

  float mean[2], rstd[2];
  if (MODE >= 1) {
    const float N = 32.f * HW_TOT;
    #pragma unroll
    for (int g = 0; g < 2; ++g) gn_stats(st, b * 2 + g, N, mean[g], rstd[g]);
  }
  if (px < HW_TOT) {
    const float* ip = in + (size_t)b * 64 * HW_TOT + px;
    #pragma unroll 2
    for (int cc = 0; cc < 8; ++cc) {
      unsigned w[4];
      #pragma unroll
      for (int jp = 0; jp < 4; ++jp) {
        float v0, v1;
        #pragma unroll
        for (int h = 0; h < 2; ++h) {
          int c = cc * 8 + jp * 2 + h;
          float v = ip[(size_t)c * HW_TOT];
          if (MODE >= 1) {
            v = silu_f((v - mean[c >> 5]) * rstd[c >> 5] * gw[c] + gb[c]);
            if (MODE == 2) v += addsrc[(size_t)(b * 64 + c) * HW_TOT + px];
          }
          if (h == 0) v0 = v; else v1 = v;
        }
        w[jp] = (unsigned)f2bf(v0) | ((unsigned)f2bf(v1) << 16);
      }
      uint4 pk = {w[0], w[1], w[2], w[3]};
      sT[tid * 8 + (cc ^ (tid & 7))] = pk;
    }
  }
  __syncthreads();
  const int o = tid & 7, pr = tid >> 3;
  #pragma unroll
  for (int i = 0; i < 8; ++i) {
    int p = i * 32 + pr;
    int gpx = p0 + p;
    if (gpx < HW_TOT) {
      int y = gpx / WOUT, x = gpx - y * WOUT;
      uint4 val = sT[p * 8 + (o ^ (p & 7))];
      *(uint4*)(outP + (((size_t)(b * HP) + y + 1) * WP + (x + 1)) * 64 + o * 8) = val;
    }
  }
}

// ---- MFMA implicit-GEMM 3x3 conv, single-staged row strip -----------------
// Block: RPB rows x WT px x 64 oc. All RPB+2 padded rows staged to LDS once;
// RPB/2 barrier-free row-pair iterations. Wave = 1 row x 32 oc (wrow=wave>>1,
// ochalf=wave&1); 36 NAMED weight v8s resident for the whole block.

#define FE18(M) M(0) M(1) M(2) M(3) M(4) M(5) M(6) M(7) M(8) M(9) M(10) \
                M(11) M(12) M(13) M(14) M(15) M(16) M(17)

#define WDL(t) \
  v8s Wa##t = ((const v8s*)wrep)[(size_t)((t) * 4 + sub) * OCT + ocbase + lx]; \
  v8s Wb##t = ((const v8s*)wrep)[(size_t)((t) * 4 + sub) * OCT + ocbase + 16 + lx];

// step t: tap = t>>1 (dy=t/6, dx=(t>>1)%3), icc-half = t&1
#define KST(t) { \
    const int col_ = xb + lx + (((t) >> 1) % 3); \
    v8s b_ = __builtin_bit_cast(v8s, sQ[((rbase + wrow + (t) / 6) * LWS + col_) * 8 + \
                                        (((((t) & 1) * 4 + sub)) ^ (col_ & 7))]); \
    a0 = __builtin_amdgcn_mfma_f32_16x16x32_bf16(Wa##t, b_, a0, 0, 0, 0); \
    a1 = __builtin_amdgcn_mfma_f32_16x16x32_bf16(Wb##t, b_, a1, 0, 0, 0); }

template<int HIN, int WIN, int WT, int NG, int RPB, int OCT, bool PSF,
         int WEU_MIN, int WEU_MAX>
__global__
__attribute__((amdgpu_flat_work_group_size(256, 256),
               amdgpu_waves_per_eu(WEU_MIN, WEU_MAX)))
void convm_k(const uint4* __restrict__ inP, const ushort* __restrict__ wrep,
             const float* __restrict__ bias, float* __restrict__ out,
             float* __restrict__ stp)
{
  constexpr int HP = HIN + 2, WP = WIN + 2;
  constexpr int LH = RPB + 2, LW = WT + 2;
  constexpr int NOCB = OCT / 64;
  constexpr int LRD = (NG * 16 + 2 > LW) ? (NG * 16 + 2) : LW;
  constexpr int LWS = (LRD + 7) & ~7;      // multiple of 8: (pix&7)==(col&7)
  constexpr int NCHUNK = LH * LWS * 8;
  static_assert(NCHUNK % 256 == 0, "staging must tile evenly");
  constexpr int STK = NCHUNK / 256;
  __shared__ uint4 sQ[NCHUNK];
  __shared__ float red[4][2];

  const int tid  = threadIdx.x;
  const int lane = tid & 63;
  const int wave = tid >> 6;
  const int sub  = lane >> 4;
  const int lx   = lane & 15;
  const int wrow = wave >> 1;              // row within pair
  const int b    = blockIdx.y / NOCB;
  const int ocb  = blockIdx.y - b * NOCB;
  constexpr int NTX = WIN / WT;
  const int tx    = blockIdx.x % NTX;
  const int ych   = blockIdx.x / NTX;
  const int x0    = tx * WT;
  const int ybase = ych * RPB;
  const int ocbase = ocb * 64 + (wave & 1) * 32;

  // ---- hoisted weights: 36 named v8s, resident for the whole block
  FE18(WDL)

  const v4f bi0 = *(const v4f*)&bias[ocbase + sub * 4];
  const v4f bi1 = *(const v4f*)&bias[ocbase + 16 + sub * 4];

  // ---- stage the whole (RPB+2)-row strip once (batched loads, one wait)
  const uint4* gbase = inP + ((size_t)(b * HP + ybase) * WP + x0) * 8;
  uint4 stg[STK];
  #pragma unroll
  for (int k = 0; k < STK; ++k) {
    int q = tid + k * 256;
    int p = q >> 3, cc = q & 7;
    int r = p / LWS, cx = p - r * LWS;
    stg[k] = gbase[((size_t)r * WP + cx) * 8 + cc];
  }
  #pragma unroll
  for (int k = 0; k < STK; ++k) {
    int q = tid + k * 256;
    int p = q >> 3, cc = q & 7;
    int cx = p - (p / LWS) * LWS;
    sQ[p * 8 + (cc ^ (cx & 7))] = stg[k];
  }
  __syncthreads();

  float sA = 0.f, qA = 0.f;

  for (int it = 0; it < RPB / 2; ++it) {
    const int rbase = it * 2;
    const int y = ybase + rbase + wrow;
    for (int xg = 0; xg < NG; ++xg) {
      const int xb = xg * 16;
      v4f a0 = bi0, a1 = bi1;
      FE18(KST)
      const int x = x0 + xb + lx;
      if ((NG * 16 == WT) || (x < WIN)) {
        #pragma unroll
        for (int s = 0; s < 2; ++s) {
          const v4f a = s ? a1 : a0;
          if (!PSF) {
            #pragma unroll
            for (int j = 0; j < 4; ++j) {
              int oc = ocbase + s * 16 + sub * 4 + j;
              out[((size_t)(b * OCT + oc) * HIN + y) * WIN + x] = a[j];
            }
          } else {
            #pragma unroll
            for (int j = 0; j < 4; ++j) {
              int oc = ocbase + s * 16 + sub * 4 + j;
              int c = oc >> 2, rr = (oc >> 1) & 1, ss = oc & 1;
              out[((size_t)(b * 64 + c) * (2 * HIN) + (2 * y + rr)) * (2 * WIN)
                  + (2 * x + ss)] = a[j];
            }
          }
          #pragma unroll
          for (int j = 0; j < 4; ++j) { sA += a[j]; qA += a[j] * a[j]; }
        }
      }
    }
  }

  // ---- GroupNorm stats: wave covers 32 oc = one group (non-PS) -----------
  #pragma unroll
  for (int o = 32; o >= 1; o >>= 1) {
    sA += __shfl_down(sA, o);
    qA += __shfl_down(qA, o);
  }
  if (lane == 0) { red[wave][0] = sA; red[wave][1] = qA; }
  __syncthreads();
  if (tid == 0) {
    float* basep = stp + ((blockIdx.x ^ blockIdx.y) & 7) * 64;
    if (PSF) {
      int g = ocb >> 1;
      atomicAdd(&basep[(b * 2 + g) * 2 + 0],
                red[0][0] + red[1][0] + red[2][0] + red[3][0]);
      atomicAdd(&basep[(b * 2 + g) * 2 + 1],
                red[0][1] + red[1][1] + red[2][1] + red[3][1]);
    } else {
      atomicAdd(&basep[(b * 2 + 0) * 2 + 0], red[0][0] + red[2][0]);
      atomicAdd(&basep[(b * 2 + 0) * 2 + 1], red[0][1] + red[2][1]);
      atomicAdd(&basep[(b * 2 + 1) * 2 + 0], red[1][0] + red[3][0]);
      atomicAdd(&basep[(b * 2 + 1) * 2 + 1], red[1][1] + red[3][1]);
    }
  }
}

// ---- readout: Y[b,o,pix] = rb[o] + sum_c GN_SiLU(D)[b,c,pix] * rw[o,c] ----
__global__ void readout_k(const float* __restrict__ D, const float* __restrict__ st,
                          const float* __restrict__ gw, const float* __restrict__ gb,
                          const float* __restrict__ rw, const float* __restrict__ rb,
                          float* __restrict__ Y)
{
  int idx = blockIdx.x * 256 + threadIdx.x;
  if (idx >= 16 * 25600) return;
  int b = idx / 25600, pix = idx - b * 25600;
  const float N = 32.f * 25600.f;
  float mean[2], rstd[2];
  #pragma unroll
  for (int g = 0; g < 2; ++g) gn_stats(st, b * 2 + g, N, mean[g], rstd[g]);
  float a0 = rb[0], a1 = rb[1], a2 = rb[2];
  const float* dp = D + (size_t)(b * 64) * 25600 + pix;
  #pragma unroll 4
  for (int c = 0; c < 64; ++c) {
    float x = dp[(size_t)c * 25600];
    float t = (x - mean[c >> 5]) * rstd[c >> 5] * gw[c] + gb[c];
    float v = silu_f(t);
    a0 = fmaf(v, rw[c], a0);
    a1 = fmaf(v, rw[64 + c], a1);
    a2 = fmaf(v, rw[128 + c], a2);
  }
  Y[(size_t)(b * 3 + 0) * 25600 + pix] = a0;
  Y[(size_t)(b * 3 + 1) * 25600 + pix] = a1;
  Y[(size_t)(b * 3 + 2) * 25600 + pix] = a2;
}

// ---- feamap: argx = conv(Y, fw, stride 4)/16, first 3 channels ------------
__global__ void feamap_k(const float* __restrict__ Y, const float* __restrict__ fw,
                         float* __restrict__ argx)
{
  int idx = blockIdx.x * 256 + threadIdx.x;
  if (idx >= 16 * 3 * 1600) return;
  int b  = idx / (3 * 1600);
  int o  = (idx / 1600) % 3;
  int ij = idx % 1600;
  int i = ij / 40, j = ij - i * 40;
  float s = 0.f;
  #pragma unroll
  for (int c = 0; c < 3; ++c)
    #pragma unroll
    for (int u = 0; u < 4; ++u)
      #pragma unroll
      for (int v = 0; v < 4; ++v)
        s += Y[((size_t)(b * 3 + c) * 160 + (4 * i + u)) * 160 + (4 * j + v)]
             * fw[((o * 3 + c) * 4 + u) * 4 + v];
  argx[idx] = s * (1.f / 16.f);
}

__global__ void nz_k(const float* __restrict__ attn, float* __restrict__ nzinv) {
  int idx = blockIdx.x * 256 + threadIdx.x;
  if (idx >= 16 * 3 * 256) return;
  const float* p = attn + (size_t)idx * 16;
  int c = 0;
  #pragma unroll
  for (int k = 0; k < 16; ++k) c += (p[k] != 0.f);
  nzinv[idx] = 1.f / ((float)c + 1e-5f);
}

__global__ void final_k(const float* __restrict__ Y, const float* __restrict__ attn,
                        const float* __restrict__ nzinv, const float* __restrict__ argx,
                        float* __restrict__ out)
{
  int idx = blockIdx.x * 256 + threadIdx.x;
  if (idx >= 16 * 3 * 25600) return;
  int bc  = idx / 25600;
  int pix = idx - bc * 25600;
  int y = pix / 160, x = pix - y * 160;
  int l  = (y / 10) * 16 + (x / 10);
  int pi = y % 10,  pj = x % 10;
  const float* ar = attn + ((size_t)bc * 256 + l) * 16;
  const float* ax = argx + (size_t)bc * 1600;
  float inv = nzinv[bc * 256 + l];
  float corr = 0.f;
  #pragma unroll
  for (int k = 0; k < 16; ++k)
    corr += ar[k] * ax[((k >> 2) * 10 + pi) * 40 + ((k & 3) * 10 + pj)];
  float yv = Y[idx];
  out[idx] = yv * (1.f + corr * inv);
}

// ---------------------------------------------------------------------------
extern "C" void kernel_launch(void* const* d_in, const int* in_sizes, int n_in,
                              void* d_out, int out_size, void* d_ws, size_t ws_size,
                              hipStream_t stream)
{
  const float* attn = (const float*)d_in[0];
  const float* hid  = (const float*)d_in[1];
  const float* enc1 = (const float*)d_in[2];
  const float* d0w  = (const float*)d_in[3];
  const float* d0b  = (const float*)d_in[4];
  const float* d0gw = (const float*)d_in[5];
  const float* d0gb = (const float*)d_in[6];
  const float* d1w  = (const float*)d_in[7];
  const float* d1b  = (const float*)d_in[8];
  const float* d1gw = (const float*)d_in[9];
  const float* d1gb = (const float*)d_in[10];
  const float* d2w  = (const float*)d_in[11];
  const float* d2b  = (const float*)d_in[12];
  const float* d2gw = (const float*)d_in[13];
  const float* d2gb = (const float*)d_in[14];
  const float* d3w  = (const float*)d_in[15];
  const float* d3b  = (const float*)d_in[16];
  const float* d3gw = (const float*)d_in[17];
  const float* d3gb = (const float*)d_in[18];
  const float* rw   = (const float*)d_in[19];
  const float* rb   = (const float*)d_in[20];
  const float* fw   = (const float*)d_in[21];

  float* ws = (float*)d_ws;
  size_t o = 0;
  float* bufA  = ws + o; o += (size_t)16 * 64 * 80 * 80;       // A / Bb / Y+argx+nzv
  float* bufAp = ws + o; o += (size_t)16 * 82 * 82 * 64 / 2;   // Ap / Bp  (bf16)
  float* bufC  = ws + o; o += (size_t)16 * 64 * 160 * 160;     // Cb / Db
  float* bufCp = ws + o; o += (size_t)16 * 162 * 162 * 64 / 2; // Cp (bf16)
  float* hidPf = ws + o; o += (size_t)16 * 42 * 42 * 64 / 2;   // hidP (bf16)
  float* st    = ws + o; o += 4 * 512;                         // slotted stats
  float* w0f   = ws + o; o += (size_t)72 * 256 * 8 / 2;
  float* w1f   = ws + o; o += (size_t)72 * 64 * 8 / 2;
  float* w2f   = ws + o; o += (size_t)72 * 256 * 8 / 2;
  float* w3f   = ws + o; o += (size_t)72 * 64 * 8 / 2;

  float*  A    = bufA;
  float*  Bb   = bufA;
  ushort* Ap   = (ushort*)bufAp;
  ushort* Bp   = (ushort*)bufAp;
  float*  Cb   = bufC;
  float*  Db   = bufC;
  ushort* Cp   = (ushort*)bufCp;
  ushort* hidP = (ushort*)hidPf;
  float*  Y    = bufA;
  float*  argx = bufA + (size_t)16 * 3 * 25600;
  float*  nzv  = argx + (size_t)16 * 3 * 1600;
  ushort* wr0  = (ushort*)w0f;
  ushort* wr1  = (ushort*)w1f;
  ushort* wr2  = (ushort*)w2f;
  ushort* wr3  = (ushort*)w3f;

  zero_k<<<8, 256, 0, stream>>>(st, 4 * 512);

  repackw_k<256><<<(256 * 576 + 255) / 256, 256, 0, stream>>>(d0w, wr0);
  repackw_k<64><<<(64 * 576 + 255) / 256, 256, 0, stream>>>(d1w, wr1);
  repackw_k<256><<<(256 * 576 + 255) / 256, 256, 0, stream>>>(d2w, wr2);
  repackw_k<64><<<(64 * 576 + 255) / 256, 256, 0, stream>>>(d3w, wr3);

  // borders (zeroed every call; act kernels write interiors only)
  border_k<42, 42><<<(16 * 42 * 42 + 255) / 256, 256, 0, stream>>>(hidP);
  border_k<82, 82><<<(16 * 82 * 82 + 255) / 256, 256, 0, stream>>>(Ap);
  border_k<162, 162><<<(16 * 162 * 162 + 255) / 256, 256, 0, stream>>>(Cp);

  // pad hid -> hidP (NHWC bf16)
  act_k<1600, 40, 0><<<16 * 7, 256, 0, stream>>>(hid, nullptr, nullptr, nullptr,
                                                 nullptr, hidP);

  // stage 0: conv(hidP)+PS -> A, stats st0 (40x40, OC=256, WT=40 NG=3 RPB=10)
  convm_k<40, 40, 40, 3, 10, 256, true, 1, 1>
    <<<dim3(4, 16 * 4), 256, 0, stream>>>((const uint4*)hidP, wr0, d0b, A,
                                          st + 0 * 512);

  // act1 -> Ap
  act_k<6400, 80, 1><<<16 * 25, 256, 0, stream>>>(A, st + 0 * 512, d0gw, d0gb,
                                                  nullptr, Ap);
  // stage 1: conv(Ap) -> Bb, stats st1 (80x80: 5 x-strips x 8 y-chunks)
  convm_k<80, 80, 16, 1, 10, 64, false, 2, 2>
    <<<dim3(40, 16), 256, 0, stream>>>((const uint4*)Ap, wr1, d1b, Bb,
                                       st + 1 * 512);

  // act2 -> Bp
  act_k<6400, 80, 1><<<16 * 25, 256, 0, stream>>>(Bb, st + 1 * 512, d1gw, d1gb,
                                                  nullptr, Bp);
  // stage 2: conv(Bp)+PS -> Cb, stats st2
  convm_k<80, 80, 16, 1, 10, 256, true, 2, 2>
    <<<dim3(40, 16 * 4), 256, 0, stream>>>((const uint4*)Bp, wr2, d2b, Cb,
                                           st + 2 * 512);

  // act3 (+enc1) -> Cp
  act_k<25600, 160, 2><<<16 * 100, 256, 0, stream>>>(Cb, st + 2 * 512, d2gw,
                                                     d2gb, enc1, Cp);
  // stage 3: conv(Cp) -> Db, stats st3 (160x160: 10 x-strips x 16 y-chunks)
  convm_k<160, 160, 16, 1, 10, 64, false, 2, 2>
    <<<dim3(160, 16), 256, 0, stream>>>((const uint4*)Cp, wr3, d3b, Db,
                                        st + 3 * 512);

  // readout -> Y
  readout_k<<<(16 * 25600 + 255) / 256, 256, 0, stream>>>(Db, st + 3 * 512,
      d3gw, d3gb, rw, rb, Y);

  feamap_k<<<(16 * 3 * 1600 + 255) / 256, 256, 0, stream>>>(Y, fw, argx);
  nz_k<<<(16 * 3 * 256 + 255) / 256, 256, 0, stream>>>(attn, nzv);
  final_k<<<(16 * 3 * 25600 + 255) / 256, 256, 0, stream>>>(Y, attn, nzv, argx,
      (float*)d_out);
}